// Round 8
// baseline (306.863 us; speedup 1.0000x reference)
//
#include <hip/hip_runtime.h>

// AFM layer, MI355X gfx950.
// out[b] = sum_p attn_p * s_p,  s_p = sum_d x[i,d]x[j,d]p[d]
// R8: stall-bound within wave (R7 showed TLP x2 => no change: ~12 waves/CU,
// VALUBusy ~55% invariant). Fill per-wave stalls with ILP: TWO j-rows per
// body sharing one xi -> 2 independent MFMA/dot chains interleaved. Unlike
// R6 (full 2-batch streams, spilled), only transient state is doubled
// (pr2 + C2 ~ +32 regs); all persistent frags shared.
// Structure from R7: 2 waves per batch (role split), 2 batches per block,
// one LDS X-copy per batch (stride-76 rows, b64 reads, measured 0 conflicts),
// tiny LDS reduce to combine roles.
// Pair schedule per batch (25 bodies, 780/800 slots):
//   t=1..15 : 32-rotation (nl,(nl+t)&31) all-valid (prod symmetric);
//   t=16    : half-rotation, nl<16;  t=17..24: uniform rows 32..39;
//   cleanup : 8-triangle of fields 32..39 (28 pairs, closed-form unrank).
// Role 0: duals (1,2)..(11,12). Role 1: duals (13,14)..(23,24) + cleanup.
// __launch_bounds__(256,4): (256,8) strangles allocator -> spill (R3).

typedef _Float16 f16;
typedef f16 f16x2 __attribute__((ext_vector_type(2)));
typedef f16 f16x4 __attribute__((ext_vector_type(4)));
typedef f16 f16x8 __attribute__((ext_vector_type(8)));
typedef float fx16 __attribute__((ext_vector_type(16)));

#define NF 40
#define NB 8192
#define STR 76   // f16 elements per LDS row (152 B) — conflict-free (R2)

union V8 { f16x8 v8; f16x4 v4[2]; f16x2 v2[4]; };

__global__ __launch_bounds__(256, 4) void afm_kernel(
    const float* __restrict__ x,   // [8192,40,64]
    const float* __restrict__ W1,  // [64,32]
    const float* __restrict__ b1,  // [32]
    const float* __restrict__ w2,  // [32]
    const float* __restrict__ p,   // [64]
    float* __restrict__ out)       // [8192]
{
    __shared__ f16 xh[2][NF * STR];     // 2 batches x 40 x 76 f16 = 12,160 B
    __shared__ float red[2][2][2];      // [batch][role][aW,aS]

    const int tid  = threadIdx.x;
    const int wid  = tid >> 6;
    const int lane = tid & 63;
    const int bl   = wid >> 1;          // batch-local 0/1
    const int role = wid & 1;           // 0: t=1..12, 1: t=13..24 + cleanup
    const int b0   = blockIdx.x * 2;

    f16* Xs = &xh[bl][0];

    // ---- stage 2 batches (5120 floats) -> LDS f16, stride-76 rows ----
    const float4* xb = (const float4*)(x + (size_t)b0 * (NF * 64));
#pragma unroll
    for (int t = 0; t < 3; ++t) {
        int g = t * 256 + tid;                 // granule 0..639 (8 f16 each)
        if (g < 640) {
            float4 v0 = xb[g * 2];
            float4 v1 = xb[g * 2 + 1];
            f16x4 lo = { (f16)v0.x, (f16)v0.y, (f16)v0.z, (f16)v0.w };
            f16x4 hi = { (f16)v1.x, (f16)v1.y, (f16)v1.z, (f16)v1.w };
            int bsel = (g >= 320);
            int gi = g - (bsel ? 320 : 0);
            int row = gi >> 3, gg = gi & 7;
            f16* dst = &xh[bsel][0] + row * STR + gg * 8;
            *(f16x4*)dst = lo;                 // 8B-aligned b64 writes
            *(f16x4*)(dst + 4) = hi;
        }
    }
    __syncthreads();

    const int nl = lane & 31;   // MFMA column / field index base
    const int hh = lane >> 5;   // wave half -> k sub-block + a-row group
    const int h8 = hh * 8;

    // ---- A-frags: W1^T, A[m=a][k=h8+j], d = kt*16 + h8 + j ----
    f16x8 w1f[4];
#pragma unroll
    for (int kt = 0; kt < 4; ++kt)
#pragma unroll
        for (int j = 0; j < 8; ++j)
            w1f[kt][j] = (f16)W1[(kt * 16 + h8 + j) * 32 + nl];

    // ---- p packed to match prod-frag element order (for fdot2) ----
    f16x2 pp[16];
#pragma unroll
    for (int kt = 0; kt < 4; ++kt)
#pragma unroll
        for (int m = 0; m < 4; ++m) {
            f16x2 t2 = { (f16)p[kt * 16 + h8 + 2 * m], (f16)p[kt * 16 + h8 + 2 * m + 1] };
            pp[kt * 4 + m] = t2;
        }

    // ---- b1 as persistent C-frag; w2*log2e packed f16 (exp2 direct) ----
    fx16 b1C;
    f16x2 w2h[8];
#pragma unroll
    for (int r = 0; r < 16; ++r) {
        int a = (r & 3) + 8 * (r >> 2) + 4 * hh;
        b1C[r] = b1[a];
    }
#pragma unroll
    for (int m = 0; m < 8; ++m) {
        int r = 2 * m;
        int a = (r & 3) + 8 * (r >> 2) + 4 * hh;
        f16x2 t2 = { (f16)(w2[a] * 1.44269504f), (f16)(w2[a + 1] * 1.44269504f) };
        w2h[m] = t2;
    }

    // ---- xi frags for row nl ----
    f16x4 xif[8];
    {
        const f16* src = Xs + nl * STR + h8;
#pragma unroll
        for (int kt = 0; kt < 4; ++kt) {
            xif[2 * kt]     = *(const f16x4*)(src + kt * 16);
            xif[2 * kt + 1] = *(const f16x4*)(src + kt * 16 + 4);
        }
    }

    float accW = 0.f, accWS = 0.f;

    // Dual-body: two j-rows sharing xi -> two independent chains interleave.
    auto body2 = [&](const f16x4* xi, int j1, int j2, bool v1, bool v2) {
        const f16* base1 = Xs + j1 * STR + h8;
        const f16* base2 = Xs + j2 * STR + h8;
        V8 pA[4], pB[4];
#pragma unroll
        for (int kt = 0; kt < 4; ++kt) {
            f16x4 a0 = *(const f16x4*)(base1 + kt * 16);      // ds_read_b64
            f16x4 a1 = *(const f16x4*)(base1 + kt * 16 + 4);
            f16x4 c0 = *(const f16x4*)(base2 + kt * 16);
            f16x4 c1 = *(const f16x4*)(base2 + kt * 16 + 4);
            pA[kt].v4[0] = xi[2 * kt] * a0;                    // v_pk_mul_f16
            pA[kt].v4[1] = xi[2 * kt + 1] * a1;
            pB[kt].v4[0] = xi[2 * kt] * c0;
            pB[kt].v4[1] = xi[2 * kt + 1] * c1;
        }
        // two independent MFMA chains (interleaved issue)
        fx16 CA = __builtin_amdgcn_mfma_f32_32x32x16_f16(w1f[0], pA[0].v8, b1C, 0, 0, 0);
        fx16 CB = __builtin_amdgcn_mfma_f32_32x32x16_f16(w1f[0], pB[0].v8, b1C, 0, 0, 0);
        CA = __builtin_amdgcn_mfma_f32_32x32x16_f16(w1f[1], pA[1].v8, CA, 0, 0, 0);
        CB = __builtin_amdgcn_mfma_f32_32x32x16_f16(w1f[1], pB[1].v8, CB, 0, 0, 0);
        CA = __builtin_amdgcn_mfma_f32_32x32x16_f16(w1f[2], pA[2].v8, CA, 0, 0, 0);
        CB = __builtin_amdgcn_mfma_f32_32x32x16_f16(w1f[2], pB[2].v8, CB, 0, 0, 0);
        CA = __builtin_amdgcn_mfma_f32_32x32x16_f16(w1f[3], pA[3].v8, CA, 0, 0, 0);
        CB = __builtin_amdgcn_mfma_f32_32x32x16_f16(w1f[3], pB[3].v8, CB, 0, 0, 0);
        // sp partials: 8 parallel fdot2 trees (4 per pair)
        float sA0 = 0.f, sA1 = 0.f, sA2 = 0.f, sA3 = 0.f;
        float sB0 = 0.f, sB1 = 0.f, sB2 = 0.f, sB3 = 0.f;
#pragma unroll
        for (int m = 0; m < 4; ++m) {
            sA0 = __builtin_amdgcn_fdot2(pA[0].v2[m], pp[m],      sA0, false);
            sB0 = __builtin_amdgcn_fdot2(pB[0].v2[m], pp[m],      sB0, false);
            sA1 = __builtin_amdgcn_fdot2(pA[1].v2[m], pp[4 + m],  sA1, false);
            sB1 = __builtin_amdgcn_fdot2(pB[1].v2[m], pp[4 + m],  sB1, false);
            sA2 = __builtin_amdgcn_fdot2(pA[2].v2[m], pp[8 + m],  sA2, false);
            sB2 = __builtin_amdgcn_fdot2(pB[2].v2[m], pp[8 + m],  sB2, false);
            sA3 = __builtin_amdgcn_fdot2(pA[3].v2[m], pp[12 + m], sA3, false);
            sB3 = __builtin_amdgcn_fdot2(pB[3].v2[m], pp[12 + m], sB3, false);
        }
        float spA = (sA0 + sA1) + (sA2 + sA3);
        float spB = (sB0 + sB1) + (sB2 + sB3);
        // logits: relu(h).(w2*log2e) packed f16, 2 trees per pair
        const f16x2 z2 = { (f16)0.f, (f16)0.f };
        float lA0 = 0.f, lA1 = 0.f, lB0 = 0.f, lB1 = 0.f;
#pragma unroll
        for (int m = 0; m < 8; ++m) {
            f16x2 ha = __builtin_bit_cast(f16x2,
                __builtin_amdgcn_cvt_pkrtz(CA[2 * m], CA[2 * m + 1]));
            f16x2 hb = __builtin_bit_cast(f16x2,
                __builtin_amdgcn_cvt_pkrtz(CB[2 * m], CB[2 * m + 1]));
            ha = __builtin_elementwise_max(ha, z2);            // v_pk_max_f16
            hb = __builtin_elementwise_max(hb, z2);
            if (m & 1) { lA1 = __builtin_amdgcn_fdot2(ha, w2h[m], lA1, false);
                         lB1 = __builtin_amdgcn_fdot2(hb, w2h[m], lB1, false); }
            else       { lA0 = __builtin_amdgcn_fdot2(ha, w2h[m], lA0, false);
                         lB0 = __builtin_amdgcn_fdot2(hb, w2h[m], lB0, false); }
        }
        float lA = lA0 + lA1, lB = lB0 + lB1;
        lA  += __shfl_xor(lA, 32);
        lB  += __shfl_xor(lB, 32);
        spA += __shfl_xor(spA, 32);
        spB += __shfl_xor(spB, 32);
        float wA = __builtin_amdgcn_exp2f(lA);
        float wB = __builtin_amdgcn_exp2f(lB);
        if (!v1) wA = 0.f;
        if (!v2) wB = 0.f;
        accW += wA + wB;
        accWS = fmaf(wA, spA, accWS);
        accWS = fmaf(wB, spB, accWS);
    };

    // 6 dual-bodies per role: role0 t=1..12, role1 t=13..24
    const int tb = 1 + role * 12;
#pragma unroll
    for (int u = 0; u < 6; ++u) {
        int t1 = tb + 2 * u, t2 = t1 + 1;
        int j1 = (t1 <= 16) ? ((nl + t1) & 31) : (t1 + 15);
        int j2 = (t2 <= 16) ? ((nl + t2) & 31) : (t2 + 15);
        bool v1 = (t1 != 16) || (nl < 16);
        bool v2 = (t2 != 16) || (nl < 16);
        body2(xif, j1, j2, v1, v2);
    }
    if (role) {   // cleanup: 28 pairs among fields 32..39 (lanes nl<28)
        int q = nl < 28 ? nl : 27;
        float disc = 225.0f - 8.0f * (float)q;
        int ii = (int)((15.0f - sqrtf(disc)) * 0.5f);
        if (ii * (15 - ii) / 2 > q) --ii;                 // sqrt 1-ulp fixups
        if ((ii + 1) * (14 - ii) / 2 <= q) ++ii;
        int jj = q - ii * (15 - ii) / 2 + ii + 1;
        int iC = 32 + ii, jC = 32 + jj;                   // pair (iC,jC), iC<jC
        f16x4 xi2[8];
        const f16* src = Xs + iC * STR + h8;
#pragma unroll
        for (int kt = 0; kt < 4; ++kt) {
            xi2[2 * kt]     = *(const f16x4*)(src + kt * 16);
            xi2[2 * kt + 1] = *(const f16x4*)(src + kt * 16 + 4);
        }
        // single body via dual with second slot masked (reads row 32: safe)
        body2(xi2, jC, 32, nl < 28, false);
    }

    // reduce across the 32 columns (halves already identical)
#pragma unroll
    for (int m = 16; m >= 1; m >>= 1) {
        accW  += __shfl_xor(accW, m);
        accWS += __shfl_xor(accWS, m);
    }
    if (lane == 0) {
        red[bl][role][0] = accW;
        red[bl][role][1] = accWS;
    }
    __syncthreads();
    if (tid < 2) {
        float W = red[tid][0][0] + red[tid][1][0];
        float S = red[tid][0][1] + red[tid][1][1];
        out[b0 + tid] = S / W;
    }
}

extern "C" void kernel_launch(void* const* d_in, const int* in_sizes, int n_in,
                              void* d_out, int out_size, void* d_ws, size_t ws_size,
                              hipStream_t stream) {
    const float* x  = (const float*)d_in[0];
    const float* W1 = (const float*)d_in[1];
    const float* b1 = (const float*)d_in[2];
    const float* w2 = (const float*)d_in[3];
    const float* p  = (const float*)d_in[4];
    float* out = (float*)d_out;
    dim3 grid(NB / 2), block(256);
    hipLaunchKernelGGL(afm_kernel, grid, block, 0, stream, x, W1, b1, w2, p, out);
}

// Round 9
// 160.649 us; speedup vs baseline: 1.9101x; 1.9101x over previous
//
#include <hip/hip_runtime.h>

// AFM layer, MI355X gfx950.
// out[b] = sum_p attn_p * s_p,  s_p = sum_d x[i,d]x[j,d]p[d]
// R9: residency is register-capped (~3 waves/SIMD; unified VGPR+AGPR file,
// rocprof VGPR_Count hides AGPRs — R3/R6/R8 all spilled when +32 regs).
// So: cut per-body work register-neutrally. sp moved to the idle MFMA pipe:
// second MFMA chain, A = p broadcast into ALL rows, C chained from b1C.
// For every lane C2[reg0] = b1C[0] + sp  (hh=0: row0+b1[0]; hh=1: row4+b1[4];
// both cancel against the lane's own b1C[0]) -> sp = C2[0]-b1C[0] on all
// lanes, no shfl. Kills 16 fdot2 + 1 shfl + 16-VGPR pp; adds 4 uniform VGPR
// (pA) + 16 AGPR (C2). Two independent 4-MFMA chains share the pr B-frags.
// Structure = R2 (best known): 4 batches/block, 1 wave/batch, 25 bodies:
//   t=1..15 : 32-rotation (nl,(nl+t)&31) all-valid (prod symmetric);
//   t=16    : half-rotation, nl<16;  t=17..24: uniform rows 32..39;
//   cleanup : 8-triangle of fields 32..39 (28 pairs, closed-form unrank).
// LDS stride-76 rows, b64 accesses — measured 0 bank conflicts (R2/R7).
// logit: relu(h).(w2*log2e) packed f16 (cvt_pkrtz+pk_max+fdot2), exp2.
// __launch_bounds__(256,4): (256,8) strangles allocator -> spill (R3).

typedef _Float16 f16;
typedef f16 f16x2 __attribute__((ext_vector_type(2)));
typedef f16 f16x4 __attribute__((ext_vector_type(4)));
typedef f16 f16x8 __attribute__((ext_vector_type(8)));
typedef float fx16 __attribute__((ext_vector_type(16)));

#define NF 40
#define NB 8192
#define STR 76   // f16 elements per LDS row (152 B) — conflict-free (R2)

union V8 { f16x8 v8; f16x4 v4[2]; f16x2 v2[4]; };

__global__ __launch_bounds__(256, 4) void afm_kernel(
    const float* __restrict__ x,   // [8192,40,64]
    const float* __restrict__ W1,  // [64,32]
    const float* __restrict__ b1,  // [32]
    const float* __restrict__ w2,  // [32]
    const float* __restrict__ p,   // [64]
    float* __restrict__ out)       // [8192]
{
    __shared__ f16 xh[4][NF * STR];   // 4 batches x 40 x 76 f16 = 24,320 B

    const int wid  = threadIdx.x >> 6;
    const int lane = threadIdx.x & 63;
    const int b    = blockIdx.x * 4 + wid;
    f16* Xs = &xh[wid][0];

    // ---- stage x[b] -> LDS f16, stride-76 rows (coalesced float4 loads) ----
    const float4* xb = (const float4*)(x + (size_t)b * (NF * 64));
#pragma unroll
    for (int t = 0; t < 10; ++t) {
        int idx = t * 64 + lane;              // 640 float4 total
        float4 v = xb[idx];
        f16x4 h = { (f16)v.x, (f16)v.y, (f16)v.z, (f16)v.w };
        int r = idx >> 4;                      // row = idx/16
        int d = (idx & 15) * 4;                // col
        *(f16x4*)(Xs + r * STR + d) = h;       // 8B-aligned b64 write
    }
    __syncthreads();

    const int nl = lane & 31;   // MFMA column / field index base
    const int hh = lane >> 5;   // wave half -> k sub-block + a-row group
    const int h8 = hh * 8;

    // ---- A-frags: W1^T, A[m=a][k=h8+j], d = kt*16 + h8 + j ----
    f16x8 w1f[4];
#pragma unroll
    for (int kt = 0; kt < 4; ++kt)
#pragma unroll
        for (int j = 0; j < 8; ++j)
            w1f[kt][j] = (f16)W1[(kt * 16 + h8 + j) * 32 + nl];

    // ---- p as A-frag broadcast into ALL rows: pA[kt][j] = p[kt*16+h8+j] ----
    f16x8 pA[4];
#pragma unroll
    for (int kt = 0; kt < 4; ++kt)
#pragma unroll
        for (int j = 0; j < 8; ++j)
            pA[kt][j] = (f16)p[kt * 16 + h8 + j];

    // ---- b1 as persistent C-frag; w2*log2e packed f16 (exp2 direct) ----
    fx16 b1C;
    f16x2 w2h[8];
#pragma unroll
    for (int r = 0; r < 16; ++r) {
        int a = (r & 3) + 8 * (r >> 2) + 4 * hh;
        b1C[r] = b1[a];
    }
#pragma unroll
    for (int m = 0; m < 8; ++m) {
        int r = 2 * m;
        int a = (r & 3) + 8 * (r >> 2) + 4 * hh;
        f16x2 t2 = { (f16)(w2[a] * 1.44269504f), (f16)(w2[a + 1] * 1.44269504f) };
        w2h[m] = t2;
    }
    const float b1c0 = b1C[0];   // per-lane: b1[0] (hh=0) / b1[4] (hh=1)

    // ---- xi frags for row nl (held in regs for t=1..24) ----
    f16x4 xif[8];
    {
        const f16* src = Xs + nl * STR + h8;
#pragma unroll
        for (int kt = 0; kt < 4; ++kt) {
            xif[2 * kt]     = *(const f16x4*)(src + kt * 16);
            xif[2 * kt + 1] = *(const f16x4*)(src + kt * 16 + 4);
        }
    }

    float accW = 0.f, accWS = 0.f;

    auto body = [&](const f16x4* xi, int jrow, bool valid) {
        const f16* base = Xs + jrow * STR + h8;
        V8 pr[4];
#pragma unroll
        for (int kt = 0; kt < 4; ++kt) {
            f16x4 a0 = *(const f16x4*)(base + kt * 16);       // ds_read_b64
            f16x4 a1 = *(const f16x4*)(base + kt * 16 + 4);
            pr[kt].v4[0] = xi[2 * kt] * a0;                    // v_pk_mul_f16
            pr[kt].v4[1] = xi[2 * kt + 1] * a1;
        }
        // chain 1: h = W1^T prod + b1;  chain 2: sp-row = p.prod + b1C
        fx16 C  = __builtin_amdgcn_mfma_f32_32x32x16_f16(w1f[0], pr[0].v8, b1C, 0, 0, 0);
        fx16 C2 = __builtin_amdgcn_mfma_f32_32x32x16_f16(pA[0],  pr[0].v8, b1C, 0, 0, 0);
        C  = __builtin_amdgcn_mfma_f32_32x32x16_f16(w1f[1], pr[1].v8, C,  0, 0, 0);
        C2 = __builtin_amdgcn_mfma_f32_32x32x16_f16(pA[1],  pr[1].v8, C2, 0, 0, 0);
        C  = __builtin_amdgcn_mfma_f32_32x32x16_f16(w1f[2], pr[2].v8, C,  0, 0, 0);
        C2 = __builtin_amdgcn_mfma_f32_32x32x16_f16(pA[2],  pr[2].v8, C2, 0, 0, 0);
        C  = __builtin_amdgcn_mfma_f32_32x32x16_f16(w1f[3], pr[3].v8, C,  0, 0, 0);
        C2 = __builtin_amdgcn_mfma_f32_32x32x16_f16(pA[3],  pr[3].v8, C2, 0, 0, 0);
        float sp = C2[0] - b1c0;   // valid on every lane (rows 0/4 trick)
        // logit partial: relu(h).(w2*log2e) packed f16, 2 parallel trees
        const f16x2 z2 = { (f16)0.f, (f16)0.f };
        float l0 = 0.f, l1 = 0.f;
#pragma unroll
        for (int m = 0; m < 8; ++m) {
            f16x2 hm = __builtin_bit_cast(f16x2,
                __builtin_amdgcn_cvt_pkrtz(C[2 * m], C[2 * m + 1]));
            hm = __builtin_elementwise_max(hm, z2);            // v_pk_max_f16
            if (m & 1) l1 = __builtin_amdgcn_fdot2(hm, w2h[m], l1, false);
            else       l0 = __builtin_amdgcn_fdot2(hm, w2h[m], l0, false);
        }
        float l = l0 + l1;
        l += __shfl_xor(l, 32);                 // combine a-halves
        float w = __builtin_amdgcn_exp2f(l);    // max-free softmax (|l| small)
        if (!valid) w = 0.f;
        accW += w;
        accWS = fmaf(w, sp, accWS);
    };

    // Phase A: 32-rotation (t=1..15 full, t=16 half)
    for (int t = 1; t <= 15; ++t)
        body(xif, (nl + t) & 31, true);
    body(xif, (nl + 16) & 31, nl < 16);

    // Phase B: i = nl < 32 <= j, wave-uniform row
    for (int u = 0; u < 8; ++u)
        body(xif, 32 + u, true);

    // Phase C: 28 pairs among fields 32..39 (lanes nl<28)
    {
        int q = nl < 28 ? nl : 27;
        float disc = 225.0f - 8.0f * (float)q;
        int ii = (int)((15.0f - sqrtf(disc)) * 0.5f);
        if (ii * (15 - ii) / 2 > q) --ii;                 // sqrt 1-ulp fixups
        if ((ii + 1) * (14 - ii) / 2 <= q) ++ii;
        int jj = q - ii * (15 - ii) / 2 + ii + 1;
        int iC = 32 + ii, jC = 32 + jj;                   // pair (iC,jC), iC<jC
        f16x4 xi2[8];
        const f16* src = Xs + iC * STR + h8;
#pragma unroll
        for (int kt = 0; kt < 4; ++kt) {
            xi2[2 * kt]     = *(const f16x4*)(src + kt * 16);
            xi2[2 * kt + 1] = *(const f16x4*)(src + kt * 16 + 4);
        }
        body(xi2, jC, nl < 28);
    }

    // reduce across the 32 columns (halves already identical)
#pragma unroll
    for (int m = 16; m >= 1; m >>= 1) {
        accW  += __shfl_xor(accW, m);
        accWS += __shfl_xor(accWS, m);
    }
    if (lane == 0) out[b] = accWS / accW;
}

extern "C" void kernel_launch(void* const* d_in, const int* in_sizes, int n_in,
                              void* d_out, int out_size, void* d_ws, size_t ws_size,
                              hipStream_t stream) {
    const float* x  = (const float*)d_in[0];
    const float* W1 = (const float*)d_in[1];
    const float* b1 = (const float*)d_in[2];
    const float* w2 = (const float*)d_in[3];
    const float* p  = (const float*)d_in[4];
    float* out = (float*)d_out;
    dim3 grid(NB / 4), block(256);
    hipLaunchKernelGGL(afm_kernel, grid, block, 0, stream, x, W1, b1, w2, p, out);
}